// Round 6
// baseline (4097.834 us; speedup 1.0000x reference)
//
#include <hip/hip_runtime.h>

#define NN 100000
#define NE 1600000
#define D  128
#define R  5
#define L  3
#define NR (NN * R)          // 500000 segments
#define NB1 489              // ceil(NR / 1024)
#define PADK 136             // bf16 per LDS A-row (128 + 8 pad)
#define TR 64                // tile rows (nodes per block)
#define FSTR 131             // fp32 LDS accum row stride (odd -> banks spread)

typedef __attribute__((ext_vector_type(8))) short bf16x8;
typedef __attribute__((ext_vector_type(4))) float f32x4;

// ============================================================================
// Prepass: CSR keyed by seg = rel*NN + dst.  Edge payload packs src (20b) and
// dst&63 (block-local row, 6b) into one int: one load per edge in the layer.
// ============================================================================
__global__ __launch_bounds__(256) void count_kernel(const int* __restrict__ dst,
                                                    const int* __restrict__ et,
                                                    int* __restrict__ cnt) {
    int e = blockIdx.x * 256 + threadIdx.x;
    if (e < NE) atomicAdd(&cnt[et[e] * NN + dst[e]], 1);
}

__global__ __launch_bounds__(256) void scan1_kernel(const int* __restrict__ cnt,
                                                    int* __restrict__ pos,
                                                    int* __restrict__ bsum) {
    __shared__ int sh[256];
    const int b = blockIdx.x, t = threadIdx.x;
    const int base = b * 1024 + t * 4;
    int v[4], s = 0;
#pragma unroll
    for (int i = 0; i < 4; ++i) {
        v[i] = (base + i < NR) ? cnt[base + i] : 0;
        s += v[i];
    }
    sh[t] = s;
    __syncthreads();
    for (int off = 1; off < 256; off <<= 1) {
        int x = (t >= off) ? sh[t - off] : 0;
        __syncthreads();
        sh[t] += x;
        __syncthreads();
    }
    int run = sh[t] - s;
    if (t == 255) bsum[b] = sh[255];
#pragma unroll
    for (int i = 0; i < 4; ++i) {
        if (base + i < NR) pos[base + i] = run;
        run += v[i];
    }
}

__global__ __launch_bounds__(512) void scan2_kernel(const int* __restrict__ bsum,
                                                    int* __restrict__ boff) {
    __shared__ int sh[512];
    const int t = threadIdx.x;
    int v = (t < NB1) ? bsum[t] : 0;
    sh[t] = v;
    __syncthreads();
    for (int off = 1; off < 512; off <<= 1) {
        int x = (t >= off) ? sh[t - off] : 0;
        __syncthreads();
        sh[t] += x;
        __syncthreads();
    }
    if (t < NB1) boff[t] = sh[t] - v;
}

__global__ __launch_bounds__(256) void scan3_kernel(const int* __restrict__ pos,
                                                    const int* __restrict__ boff,
                                                    const int* __restrict__ cnt,
                                                    int* __restrict__ ptr,
                                                    int* __restrict__ fill,
                                                    float* __restrict__ inv) {
    int i = blockIdx.x * 256 + threadIdx.x;
    if (i < NR) {
        int p = pos[i] + boff[i >> 10];
        ptr[i] = p;
        fill[i] = p;
        int c = cnt[i];
        inv[i] = 1.0f / (float)(c > 0 ? c : 1);
    }
    if (i == 0) ptr[NR] = NE;
}

__global__ __launch_bounds__(256) void bucket_kernel(const int* __restrict__ src,
                                                     const int* __restrict__ dst,
                                                     const int* __restrict__ et,
                                                     int* __restrict__ fill,
                                                     int* __restrict__ ssrc) {
    int e = blockIdx.x * 256 + threadIdx.x;
    if (e < NE) {
        int d = dst[e];
        int p = atomicAdd(&fill[et[e] * NN + d], 1);
        ssrc[p] = src[e] | ((d & 63) << 20);
    }
}

// ============================================================================
// Weight prep: transpose + exact bf16 hi/lo split. Wt[mat][col][k].
// ============================================================================
__device__ __forceinline__ void split2(float f0, float f1, uint& hw, uint& lw) {
    uint b0 = __builtin_bit_cast(uint, f0), b1 = __builtin_bit_cast(uint, f1);
    uint h0 = b0 >> 16, h1 = b1 >> 16;
    float r0 = f0 - __builtin_bit_cast(float, h0 << 16);
    float r1 = f1 - __builtin_bit_cast(float, h1 << 16);
    hw = h0 | (h1 << 16);
    lw = (__builtin_bit_cast(uint, r0) >> 16) | (__builtin_bit_cast(uint, r1) & 0xFFFF0000u);
}

__global__ __launch_bounds__(256) void wprep_kernel(const float* __restrict__ W,
                                                    const float* __restrict__ roots,
                                                    ushort* __restrict__ WtH,
                                                    ushort* __restrict__ WtL) {
    const int mat = blockIdx.x;        // 0..17
    const int l = mat / 6, ph = mat % 6;
    const float* S = (ph == 0) ? roots + (size_t)l * D * D
                               : W + ((size_t)l * R + (ph - 1)) * D * D;
    const int t = threadIdx.x;
    const int dc = t & 127;
    const int half = t >> 7;
    uint* oh = (uint*)(WtH + ((size_t)mat * D + dc) * D) + half * 32;
    uint* ol = (uint*)(WtL + ((size_t)mat * D + dc) * D) + half * 32;
#pragma unroll 4
    for (int j = 0; j < 32; ++j) {
        int dk = half * 64 + j * 2;
        uint hw, lw;
        split2(S[(size_t)dk * D + dc], S[(size_t)(dk + 1) * D + dc], hw, lw);
        oh[j] = hw;
        ol[j] = lw;
    }
}

// ============================================================================
// Fused layer, edge-parallel aggregation:
//   phase 0 (root): h[node] -> split bf16 -> A-tile; MFMA vs root weights.
//   phase 1..5 (rel r): block's contiguous edge range split evenly over the
//     64 8-lane groups; each group streams full 512B h[src] rows (128B
//     contiguous per instr) and ds_add_f32's into fa[64][FSTR]; then scale by
//     inv, split bf16 in place (overlay), MFMA vs W_r.
// LDS union 34 KB -> 4 blocks/CU, 32 waves/CU. Epilogue LDS-staged.
// ============================================================================
template <int RELU>
__global__ __launch_bounds__(512, 8) void rgcn_layer(
    const float* __restrict__ h, const ushort* __restrict__ WtH,
    const ushort* __restrict__ WtL, const float* __restrict__ bias,
    const int* __restrict__ ptr, const int* __restrict__ ssrc,
    const float* __restrict__ inv, float* __restrict__ out) {
    __shared__ __align__(16) ushort ABuf[2 * TR * PADK];   // 34816 B
    ushort* Ahi = ABuf;
    ushort* Alo = ABuf + TR * PADK;
    float*  fa  = (float*)ABuf;                            // overlay, 64*FSTR

    const int tid  = threadIdx.x;
    const int row0 = blockIdx.x * TR;
    const int lane = tid & 63;
    const int wv   = tid >> 6;
    const int wr   = wv & 1;           // 32-row group
    const int wc   = wv >> 1;          // 32-col group
    const int g    = tid >> 3;         // 0..63: node slot / edge group
    const int aq   = tid & 7;          // row-chunk lane
    const int lr   = lane & 15;
    const int lg   = lane >> 4;

    f32x4 acc[2][2];
#pragma unroll
    for (int m = 0; m < 2; ++m)
#pragma unroll
        for (int n = 0; n < 2; ++n) acc[m][n] = (f32x4){0.f, 0.f, 0.f, 0.f};

#pragma unroll 1
    for (int ph = 0; ph < 6; ++ph) {
        __syncthreads();   // previous phase done reading A-tile / fa overlay

        if (ph == 0) {
            // ---- root: direct load, split, store ----
            const int node = row0 + g;
            uint4 H0 = {0,0,0,0}, L0 = {0,0,0,0}, H1 = {0,0,0,0}, L1 = {0,0,0,0};
            if (node < NN) {
                const float4* hp = (const float4*)(h + (size_t)node * D + aq * 16);
                float4 v[4];
#pragma unroll
                for (int i = 0; i < 4; ++i) {
                    float4 t4 = hp[i];
                    if (RELU) {
                        t4.x = fmaxf(t4.x, 0.f); t4.y = fmaxf(t4.y, 0.f);
                        t4.z = fmaxf(t4.z, 0.f); t4.w = fmaxf(t4.w, 0.f);
                    }
                    v[i] = t4;
                }
                split2(v[0].x, v[0].y, H0.x, L0.x);
                split2(v[0].z, v[0].w, H0.y, L0.y);
                split2(v[1].x, v[1].y, H0.z, L0.z);
                split2(v[1].z, v[1].w, H0.w, L0.w);
                split2(v[2].x, v[2].y, H1.x, L1.x);
                split2(v[2].z, v[2].w, H1.y, L1.y);
                split2(v[3].x, v[3].y, H1.z, L1.z);
                split2(v[3].z, v[3].w, H1.w, L1.w);
            }
            const int base = g * PADK + aq * 16;
            *(uint4*)&Ahi[base]     = H0;
            *(uint4*)&Ahi[base + 8] = H1;
            *(uint4*)&Alo[base]     = L0;
            *(uint4*)&Alo[base + 8] = L1;
        } else {
            // ---- zero fp32 accum tile ----
            float4* fz = (float4*)fa;
#pragma unroll
            for (int i = 0; i < 5; ++i) {
                int idx = tid + i * 512;
                if (idx < (TR * FSTR) / 4 + 1) fz[idx] = make_float4(0.f, 0.f, 0.f, 0.f);
            }
            __syncthreads();

            // ---- edge-parallel scatter ----
            const int segBase = (ph - 1) * NN;
            const int hi_node = (row0 + TR > NN) ? NN : row0 + TR;
            const int e0 = ptr[segBase + row0];
            const int e1 = ptr[segBase + hi_node];
            for (int e = e0 + g; e < e1; e += 64) {
                const uint w = (uint)ssrc[e];
                const int s  = w & 0xFFFFF;
                const int dl = w >> 20;
                const float4* hp = (const float4*)(h + (size_t)s * D);
                float4 t0 = hp[aq], t1 = hp[8 + aq], t2 = hp[16 + aq], t3 = hp[24 + aq];
                if (RELU) {
                    t0.x = fmaxf(t0.x, 0.f); t0.y = fmaxf(t0.y, 0.f);
                    t0.z = fmaxf(t0.z, 0.f); t0.w = fmaxf(t0.w, 0.f);
                    t1.x = fmaxf(t1.x, 0.f); t1.y = fmaxf(t1.y, 0.f);
                    t1.z = fmaxf(t1.z, 0.f); t1.w = fmaxf(t1.w, 0.f);
                    t2.x = fmaxf(t2.x, 0.f); t2.y = fmaxf(t2.y, 0.f);
                    t2.z = fmaxf(t2.z, 0.f); t2.w = fmaxf(t2.w, 0.f);
                    t3.x = fmaxf(t3.x, 0.f); t3.y = fmaxf(t3.y, 0.f);
                    t3.z = fmaxf(t3.z, 0.f); t3.w = fmaxf(t3.w, 0.f);
                }
                float* fr = fa + dl * FSTR + aq * 4;
                atomicAdd(fr + 0,        t0.x); atomicAdd(fr + 1,        t0.y);
                atomicAdd(fr + 2,        t0.z); atomicAdd(fr + 3,        t0.w);
                atomicAdd(fr + 32 + 0,   t1.x); atomicAdd(fr + 32 + 1,   t1.y);
                atomicAdd(fr + 32 + 2,   t1.z); atomicAdd(fr + 32 + 3,   t1.w);
                atomicAdd(fr + 64 + 0,   t2.x); atomicAdd(fr + 64 + 1,   t2.y);
                atomicAdd(fr + 64 + 2,   t2.z); atomicAdd(fr + 64 + 3,   t2.w);
                atomicAdd(fr + 96 + 0,   t3.x); atomicAdd(fr + 96 + 1,   t3.y);
                atomicAdd(fr + 96 + 2,   t3.z); atomicAdd(fr + 96 + 3,   t3.w);
            }
            __syncthreads();

            // ---- scale by inv, read out (before overlay write) ----
            const int node = row0 + g;
            const float sc = (node < NN) ? inv[segBase + node] : 0.f;
            float vv[16];
            const float* fr = fa + g * FSTR + aq * 4;
#pragma unroll
            for (int i = 0; i < 4; ++i) {
                vv[i * 4 + 0] = fr[i * 32 + 0] * sc;
                vv[i * 4 + 1] = fr[i * 32 + 1] * sc;
                vv[i * 4 + 2] = fr[i * 32 + 2] * sc;
                vv[i * 4 + 3] = fr[i * 32 + 3] * sc;
            }
            __syncthreads();   // all fa reads done before overlay writes

            // ---- split to bf16 hi/lo, write overlay A-tile ----
#pragma unroll
            for (int i = 0; i < 4; ++i) {
                uint2 H, Lw;
                split2(vv[i * 4 + 0], vv[i * 4 + 1], H.x, Lw.x);
                split2(vv[i * 4 + 2], vv[i * 4 + 3], H.y, Lw.y);
                const int k = i * 32 + aq * 4;
                *(uint2*)&Ahi[g * PADK + k] = H;
                *(uint2*)&Alo[g * PADK + k] = Lw;
            }
        }
        __syncthreads();

        // ---- MFMA: acc += A[64x128] * Wt[ph]^T (3-term split) ----
        const ushort* BH = WtH + (size_t)ph * D * D;
        const ushort* BL = WtL + (size_t)ph * D * D;
        const int arow = wr * 32 + lr;
#pragma unroll
        for (int ks = 0; ks < 4; ++ks) {
            const int ak = ks * 32 + lg * 8;
            const bf16x8 a0h = *(const bf16x8*)&Ahi[arow * PADK + ak];
            const bf16x8 a1h = *(const bf16x8*)&Ahi[(arow + 16) * PADK + ak];
            const bf16x8 a0l = *(const bf16x8*)&Alo[arow * PADK + ak];
            const bf16x8 a1l = *(const bf16x8*)&Alo[(arow + 16) * PADK + ak];
#pragma unroll
            for (int n = 0; n < 2; ++n) {
                const int bc = wc * 32 + n * 16 + lr;
                const bf16x8 bh = *(const bf16x8*)&BH[(size_t)bc * D + ak];
                const bf16x8 bl = *(const bf16x8*)&BL[(size_t)bc * D + ak];
                acc[0][n] = __builtin_amdgcn_mfma_f32_16x16x32_bf16(a0h, bh, acc[0][n], 0, 0, 0);
                acc[1][n] = __builtin_amdgcn_mfma_f32_16x16x32_bf16(a1h, bh, acc[1][n], 0, 0, 0);
                acc[0][n] = __builtin_amdgcn_mfma_f32_16x16x32_bf16(a0l, bh, acc[0][n], 0, 0, 0);
                acc[1][n] = __builtin_amdgcn_mfma_f32_16x16x32_bf16(a1l, bh, acc[1][n], 0, 0, 0);
                acc[0][n] = __builtin_amdgcn_mfma_f32_16x16x32_bf16(a0h, bl, acc[0][n], 0, 0, 0);
                acc[1][n] = __builtin_amdgcn_mfma_f32_16x16x32_bf16(a1h, bl, acc[1][n], 0, 0, 0);
            }
        }
    }

    // ---- epilogue: stage C in LDS, then contiguous 512B-row stores ----
    __syncthreads();
    float* Cs = (float*)ABuf;          // [64][128], 32 KB
#pragma unroll
    for (int m = 0; m < 2; ++m) {
        const int rb = wr * 32 + m * 16 + lg * 4;
#pragma unroll
        for (int n = 0; n < 2; ++n) {
            const int col = wc * 32 + n * 16 + lr;
#pragma unroll
            for (int vi = 0; vi < 4; ++vi)
                Cs[(rb + vi) * 128 + col] = acc[m][n][vi];
        }
    }
    __syncthreads();
#pragma unroll
    for (int r4 = 0; r4 < 4; ++r4) {
        const int fi = (r4 * 512 + tid) * 4;     // flat float idx
        const int row = fi >> 7, col = fi & 127;
        if (row0 + row < NN) {
            float4 v = *(float4*)&Cs[fi];
            const float4 b = *(const float4*)&bias[col];
            v.x += b.x; v.y += b.y; v.z += b.z; v.w += b.w;
            *(float4*)&out[(size_t)(row0 + row) * D + col] = v;
        }
    }
}

// ============================================================================
extern "C" void kernel_launch(void* const* d_in, const int* in_sizes, int n_in,
                              void* d_out, int out_size, void* d_ws, size_t ws_size,
                              hipStream_t stream) {
    const float* x      = (const float*)d_in[0];
    const int*   eidx   = (const int*)d_in[1];
    const int*   etyp   = (const int*)d_in[2];
    const float* W      = (const float*)d_in[3];   // [L][R][D][D]
    const float* roots  = (const float*)d_in[4];   // [L][D][D]
    const float* biases = (const float*)d_in[5];   // [L][D]
    float*       out    = (float*)d_out;

    const int* src = eidx;
    const int* dst = eidx + NE;

    // workspace layout (~122 MB)
    float*  bufA = (float*)d_ws;                     // N*D
    float*  bufB = bufA + (size_t)NN * D;            // N*D
    int*    ptr  = (int*)(bufB + (size_t)NN * D);    // NR+1
    int*    fill = ptr + NR + 1;                     // NR
    float*  invp = (float*)(fill + NR);              // NR
    int*    cnt  = (int*)(invp + NR);                // NR
    int*    pos  = cnt + NR;                         // NR
    int*    bsum = pos + NR;                         // 512
    int*    boff = bsum + 512;                       // 512
    int*    ssrc = boff + 512;                       // NE
    ushort* WtH  = (ushort*)(ssrc + NE);             // 18*128*128
    ushort* WtL  = WtH + (size_t)L * 6 * D * D;      // 18*128*128

    hipMemsetAsync(cnt, 0, sizeof(int) * (size_t)NR, stream);
    count_kernel<<<(NE + 255) / 256, 256, 0, stream>>>(dst, etyp, cnt);
    scan1_kernel<<<NB1, 256, 0, stream>>>(cnt, pos, bsum);
    scan2_kernel<<<1, 512, 0, stream>>>(bsum, boff);
    scan3_kernel<<<(NR + 255) / 256, 256, 0, stream>>>(pos, boff, cnt, ptr, fill, invp);
    bucket_kernel<<<(NE + 255) / 256, 256, 0, stream>>>(src, dst, etyp, fill, ssrc);
    wprep_kernel<<<L * 6, 256, 0, stream>>>(W, roots, WtH, WtL);

    const dim3 lgrid((NN + TR - 1) / TR);
    rgcn_layer<0><<<lgrid, 512, 0, stream>>>(x,    WtH + 0 * (size_t)6 * D * D,
                                             WtL + 0 * (size_t)6 * D * D, biases + 0 * D,
                                             ptr, ssrc, invp, bufA);
    rgcn_layer<1><<<lgrid, 512, 0, stream>>>(bufA, WtH + 1 * (size_t)6 * D * D,
                                             WtL + 1 * (size_t)6 * D * D, biases + 1 * D,
                                             ptr, ssrc, invp, bufB);
    rgcn_layer<1><<<lgrid, 512, 0, stream>>>(bufB, WtH + 2 * (size_t)6 * D * D,
                                             WtL + 2 * (size_t)6 * D * D, biases + 2 * D,
                                             ptr, ssrc, invp, out);
}

// Round 7
// 2667.956 us; speedup vs baseline: 1.5359x; 1.5359x over previous
//
#include <hip/hip_runtime.h>

#define NN 100000
#define NE 1600000
#define D  128
#define R  5
#define L  3
#define NR (NN * R)          // 500000 segments
#define NB1 489              // ceil(NR / 1024)
#define PADK 136             // bf16 per LDS A-row (128 + 8 pad)
#define TR 64                // tile rows (nodes per block)
#define FSTR 131             // fp32 LDS accum row stride (odd -> banks spread)

typedef __attribute__((ext_vector_type(8))) short bf16x8;
typedef __attribute__((ext_vector_type(4))) float f32x4;

// ============================================================================
// Prepass: CSR keyed by seg = rel*NN + dst.  Edge payload packs src (20b) and
// dst&63 (block-local row, 6b) into one int.
// ============================================================================
__global__ __launch_bounds__(256) void count_kernel(const int* __restrict__ dst,
                                                    const int* __restrict__ et,
                                                    int* __restrict__ cnt) {
    int e = blockIdx.x * 256 + threadIdx.x;
    if (e < NE) atomicAdd(&cnt[et[e] * NN + dst[e]], 1);
}

__global__ __launch_bounds__(256) void scan1_kernel(const int* __restrict__ cnt,
                                                    int* __restrict__ pos,
                                                    int* __restrict__ bsum) {
    __shared__ int sh[256];
    const int b = blockIdx.x, t = threadIdx.x;
    const int base = b * 1024 + t * 4;
    int v[4], s = 0;
#pragma unroll
    for (int i = 0; i < 4; ++i) {
        v[i] = (base + i < NR) ? cnt[base + i] : 0;
        s += v[i];
    }
    sh[t] = s;
    __syncthreads();
    for (int off = 1; off < 256; off <<= 1) {
        int x = (t >= off) ? sh[t - off] : 0;
        __syncthreads();
        sh[t] += x;
        __syncthreads();
    }
    int run = sh[t] - s;
    if (t == 255) bsum[b] = sh[255];
#pragma unroll
    for (int i = 0; i < 4; ++i) {
        if (base + i < NR) pos[base + i] = run;
        run += v[i];
    }
}

__global__ __launch_bounds__(512) void scan2_kernel(const int* __restrict__ bsum,
                                                    int* __restrict__ boff) {
    __shared__ int sh[512];
    const int t = threadIdx.x;
    int v = (t < NB1) ? bsum[t] : 0;
    sh[t] = v;
    __syncthreads();
    for (int off = 1; off < 512; off <<= 1) {
        int x = (t >= off) ? sh[t - off] : 0;
        __syncthreads();
        sh[t] += x;
        __syncthreads();
    }
    if (t < NB1) boff[t] = sh[t] - v;
}

__global__ __launch_bounds__(256) void scan3_kernel(const int* __restrict__ pos,
                                                    const int* __restrict__ boff,
                                                    const int* __restrict__ cnt,
                                                    int* __restrict__ ptr,
                                                    int* __restrict__ fill,
                                                    float* __restrict__ inv) {
    int i = blockIdx.x * 256 + threadIdx.x;
    if (i < NR) {
        int p = pos[i] + boff[i >> 10];
        ptr[i] = p;
        fill[i] = p;
        int c = cnt[i];
        inv[i] = 1.0f / (float)(c > 0 ? c : 1);
    }
    if (i == 0) ptr[NR] = NE;
}

__global__ __launch_bounds__(256) void bucket_kernel(const int* __restrict__ src,
                                                     const int* __restrict__ dst,
                                                     const int* __restrict__ et,
                                                     int* __restrict__ fill,
                                                     int* __restrict__ ssrc) {
    int e = blockIdx.x * 256 + threadIdx.x;
    if (e < NE) {
        int d = dst[e];
        int p = atomicAdd(&fill[et[e] * NN + d], 1);
        ssrc[p] = src[e] | ((d & 63) << 20);
    }
}

// ============================================================================
// Weight prep: transpose + exact bf16 hi/lo split. Wt[mat][col][k].
// ============================================================================
__device__ __forceinline__ void split2(float f0, float f1, uint& hw, uint& lw) {
    uint b0 = __builtin_bit_cast(uint, f0), b1 = __builtin_bit_cast(uint, f1);
    uint h0 = b0 >> 16, h1 = b1 >> 16;
    float r0 = f0 - __builtin_bit_cast(float, h0 << 16);
    float r1 = f1 - __builtin_bit_cast(float, h1 << 16);
    hw = h0 | (h1 << 16);
    lw = (__builtin_bit_cast(uint, r0) >> 16) | (__builtin_bit_cast(uint, r1) & 0xFFFF0000u);
}

__global__ __launch_bounds__(256) void wprep_kernel(const float* __restrict__ W,
                                                    const float* __restrict__ roots,
                                                    ushort* __restrict__ WtH,
                                                    ushort* __restrict__ WtL) {
    const int mat = blockIdx.x;        // 0..17
    const int l = mat / 6, ph = mat % 6;
    const float* S = (ph == 0) ? roots + (size_t)l * D * D
                               : W + ((size_t)l * R + (ph - 1)) * D * D;
    const int t = threadIdx.x;
    const int dc = t & 127;
    const int half = t >> 7;
    uint* oh = (uint*)(WtH + ((size_t)mat * D + dc) * D) + half * 32;
    uint* ol = (uint*)(WtL + ((size_t)mat * D + dc) * D) + half * 32;
#pragma unroll 4
    for (int j = 0; j < 32; ++j) {
        int dk = half * 64 + j * 2;
        uint hw, lw;
        split2(S[(size_t)dk * D + dc], S[(size_t)(dk + 1) * D + dc], hw, lw);
        oh[j] = hw;
        ol[j] = lw;
    }
}

// ============================================================================
// Fused layer, edge-parallel aggregation with NATIVE ds_add_f32:
//   phase 0 (root): h[node] -> split bf16 -> A-tile; MFMA vs root weights.
//   phase 1..5 (rel r): block's contiguous edge range divided into 64 chunks
//     (one per 8-lane group). Each group streams full 512B h[src] rows,
//     accumulates same-dst runs in registers, flushes runs with inline-asm
//     ds_add_f32 (no CAS loop!). Then scale by inv, split bf16 in place,
//     MFMA vs W_r.
// LDS union 34 KB -> 4 blocks/CU, 32 waves/CU. Epilogue LDS-staged.
// ============================================================================

// 16 native LDS float adds at vaddr + {0..12, 128.., 256.., 384..}
#define FLUSH16(vaddr, a0, a1, a2, a3)                                              \
    do {                                                                            \
        asm volatile("ds_add_f32 %0, %1 offset:0"   :: "v"(vaddr), "v"((a0).x));    \
        asm volatile("ds_add_f32 %0, %1 offset:4"   :: "v"(vaddr), "v"((a0).y));    \
        asm volatile("ds_add_f32 %0, %1 offset:8"   :: "v"(vaddr), "v"((a0).z));    \
        asm volatile("ds_add_f32 %0, %1 offset:12"  :: "v"(vaddr), "v"((a0).w));    \
        asm volatile("ds_add_f32 %0, %1 offset:128" :: "v"(vaddr), "v"((a1).x));    \
        asm volatile("ds_add_f32 %0, %1 offset:132" :: "v"(vaddr), "v"((a1).y));    \
        asm volatile("ds_add_f32 %0, %1 offset:136" :: "v"(vaddr), "v"((a1).z));    \
        asm volatile("ds_add_f32 %0, %1 offset:140" :: "v"(vaddr), "v"((a1).w));    \
        asm volatile("ds_add_f32 %0, %1 offset:256" :: "v"(vaddr), "v"((a2).x));    \
        asm volatile("ds_add_f32 %0, %1 offset:260" :: "v"(vaddr), "v"((a2).y));    \
        asm volatile("ds_add_f32 %0, %1 offset:264" :: "v"(vaddr), "v"((a2).z));    \
        asm volatile("ds_add_f32 %0, %1 offset:268" :: "v"(vaddr), "v"((a2).w));    \
        asm volatile("ds_add_f32 %0, %1 offset:384" :: "v"(vaddr), "v"((a3).x));    \
        asm volatile("ds_add_f32 %0, %1 offset:388" :: "v"(vaddr), "v"((a3).y));    \
        asm volatile("ds_add_f32 %0, %1 offset:392" :: "v"(vaddr), "v"((a3).z));    \
        asm volatile("ds_add_f32 %0, %1 offset:396" :: "v"(vaddr), "v"((a3).w));    \
    } while (0)

template <int RELU>
__global__ __launch_bounds__(512, 8) void rgcn_layer(
    const float* __restrict__ h, const ushort* __restrict__ WtH,
    const ushort* __restrict__ WtL, const float* __restrict__ bias,
    const int* __restrict__ ptr, const int* __restrict__ ssrc,
    const float* __restrict__ inv, float* __restrict__ out) {
    __shared__ __align__(16) ushort ABuf[2 * TR * PADK];   // 34816 B
    ushort* Ahi = ABuf;
    ushort* Alo = ABuf + TR * PADK;
    float*  fa  = (float*)ABuf;                            // overlay, 64*FSTR

    const int tid  = threadIdx.x;
    const int row0 = blockIdx.x * TR;
    const int lane = tid & 63;
    const int wv   = tid >> 6;
    const int wr   = wv & 1;           // 32-row group
    const int wc   = wv >> 1;          // 32-col group
    const int g    = tid >> 3;         // 0..63: node slot / edge chunk
    const int aq   = tid & 7;          // row-chunk lane
    const int lr   = lane & 15;
    const int lg   = lane >> 4;

    // LDS byte address of this thread's feature slice within a row (row 0)
    const uint fa_base = (uint)(unsigned long long)(void*)fa + (uint)(aq * 16);

    f32x4 acc[2][2];
#pragma unroll
    for (int m = 0; m < 2; ++m)
#pragma unroll
        for (int n = 0; n < 2; ++n) acc[m][n] = (f32x4){0.f, 0.f, 0.f, 0.f};

#pragma unroll 1
    for (int ph = 0; ph < 6; ++ph) {
        __syncthreads();   // previous phase done reading A-tile / fa overlay

        if (ph == 0) {
            // ---- root: direct load, split, store ----
            const int node = row0 + g;
            uint4 H0 = {0,0,0,0}, L0 = {0,0,0,0}, H1 = {0,0,0,0}, L1 = {0,0,0,0};
            if (node < NN) {
                const float4* hp = (const float4*)(h + (size_t)node * D + aq * 16);
                float4 v[4];
#pragma unroll
                for (int i = 0; i < 4; ++i) {
                    float4 t4 = hp[i];
                    if (RELU) {
                        t4.x = fmaxf(t4.x, 0.f); t4.y = fmaxf(t4.y, 0.f);
                        t4.z = fmaxf(t4.z, 0.f); t4.w = fmaxf(t4.w, 0.f);
                    }
                    v[i] = t4;
                }
                split2(v[0].x, v[0].y, H0.x, L0.x);
                split2(v[0].z, v[0].w, H0.y, L0.y);
                split2(v[1].x, v[1].y, H0.z, L0.z);
                split2(v[1].z, v[1].w, H0.w, L0.w);
                split2(v[2].x, v[2].y, H1.x, L1.x);
                split2(v[2].z, v[2].w, H1.y, L1.y);
                split2(v[3].x, v[3].y, H1.z, L1.z);
                split2(v[3].z, v[3].w, H1.w, L1.w);
            }
            const int base = g * PADK + aq * 16;
            *(uint4*)&Ahi[base]     = H0;
            *(uint4*)&Ahi[base + 8] = H1;
            *(uint4*)&Alo[base]     = L0;
            *(uint4*)&Alo[base + 8] = L1;
        } else {
            // ---- zero fp32 accum tile ----
            float4* fz = (float4*)fa;
#pragma unroll
            for (int i = 0; i < 5; ++i) {
                int idx = tid + i * 512;
                if (idx < (TR * FSTR) / 4 + 1) fz[idx] = make_float4(0.f, 0.f, 0.f, 0.f);
            }
            __syncthreads();

            // ---- edge-parallel scatter: chunk per group, run-coalesced ----
            const int segBase = (ph - 1) * NN;
            const int hi_node = (row0 + TR > NN) ? NN : row0 + TR;
            const int e0 = ptr[segBase + row0];
            const int e1 = ptr[segBase + hi_node];
            const int len = e1 - e0;
            const int eb = e0 + (len * g) / 64;
            const int ee = e0 + (len * (g + 1)) / 64;

            int cur = -1;
            float4 a0, a1, a2, a3;
            for (int e = eb; e < ee; ++e) {
                const uint w = (uint)ssrc[e];
                const int s  = w & 0xFFFFF;
                const int dl = (int)(w >> 20);
                const float4* hp = (const float4*)(h + (size_t)s * D);
                float4 t0 = hp[aq], t1 = hp[8 + aq], t2 = hp[16 + aq], t3 = hp[24 + aq];
                if (RELU) {
                    t0.x = fmaxf(t0.x, 0.f); t0.y = fmaxf(t0.y, 0.f);
                    t0.z = fmaxf(t0.z, 0.f); t0.w = fmaxf(t0.w, 0.f);
                    t1.x = fmaxf(t1.x, 0.f); t1.y = fmaxf(t1.y, 0.f);
                    t1.z = fmaxf(t1.z, 0.f); t1.w = fmaxf(t1.w, 0.f);
                    t2.x = fmaxf(t2.x, 0.f); t2.y = fmaxf(t2.y, 0.f);
                    t2.z = fmaxf(t2.z, 0.f); t2.w = fmaxf(t2.w, 0.f);
                    t3.x = fmaxf(t3.x, 0.f); t3.y = fmaxf(t3.y, 0.f);
                    t3.z = fmaxf(t3.z, 0.f); t3.w = fmaxf(t3.w, 0.f);
                }
                if (dl != cur) {
                    if (cur >= 0) {
                        const uint va = fa_base + (uint)cur * (FSTR * 4);
                        FLUSH16(va, a0, a1, a2, a3);
                    }
                    cur = dl;
                    a0 = t0; a1 = t1; a2 = t2; a3 = t3;
                } else {
                    a0.x += t0.x; a0.y += t0.y; a0.z += t0.z; a0.w += t0.w;
                    a1.x += t1.x; a1.y += t1.y; a1.z += t1.z; a1.w += t1.w;
                    a2.x += t2.x; a2.y += t2.y; a2.z += t2.z; a2.w += t2.w;
                    a3.x += t3.x; a3.y += t3.y; a3.z += t3.z; a3.w += t3.w;
                }
            }
            if (cur >= 0) {
                const uint va = fa_base + (uint)cur * (FSTR * 4);
                FLUSH16(va, a0, a1, a2, a3);
            }
            asm volatile("s_waitcnt lgkmcnt(0)" ::: "memory");
            __syncthreads();

            // ---- scale by inv, read out (before overlay write) ----
            const int node = row0 + g;
            const float sc = (node < NN) ? inv[segBase + node] : 0.f;
            float vv[16];
            const float* fr = fa + g * FSTR + aq * 4;
#pragma unroll
            for (int i = 0; i < 4; ++i) {
                vv[i * 4 + 0] = fr[i * 32 + 0] * sc;
                vv[i * 4 + 1] = fr[i * 32 + 1] * sc;
                vv[i * 4 + 2] = fr[i * 32 + 2] * sc;
                vv[i * 4 + 3] = fr[i * 32 + 3] * sc;
            }
            __syncthreads();   // all fa reads done before overlay writes

            // ---- split to bf16 hi/lo, write overlay A-tile ----
#pragma unroll
            for (int i = 0; i < 4; ++i) {
                uint2 H, Lw;
                split2(vv[i * 4 + 0], vv[i * 4 + 1], H.x, Lw.x);
                split2(vv[i * 4 + 2], vv[i * 4 + 3], H.y, Lw.y);
                const int k = i * 32 + aq * 4;
                *(uint2*)&Ahi[g * PADK + k] = H;
                *(uint2*)&Alo[g * PADK + k] = Lw;
            }
        }
        __syncthreads();

        // ---- MFMA: acc += A[64x128] * Wt[ph]^T (3-term split) ----
        const ushort* BH = WtH + (size_t)ph * D * D;
        const ushort* BL = WtL + (size_t)ph * D * D;
        const int arow = wr * 32 + lr;
#pragma unroll
        for (int ks = 0; ks < 4; ++ks) {
            const int ak = ks * 32 + lg * 8;
            const bf16x8 a0h = *(const bf16x8*)&Ahi[arow * PADK + ak];
            const bf16x8 a1h = *(const bf16x8*)&Ahi[(arow + 16) * PADK + ak];
            const bf16x8 a0l = *(const bf16x8*)&Alo[arow * PADK + ak];
            const bf16x8 a1l = *(const bf16x8*)&Alo[(arow + 16) * PADK + ak];
#pragma unroll
            for (int n = 0; n < 2; ++n) {
                const int bc = wc * 32 + n * 16 + lr;
                const bf16x8 bh = *(const bf16x8*)&BH[(size_t)bc * D + ak];
                const bf16x8 bl = *(const bf16x8*)&BL[(size_t)bc * D + ak];
                acc[0][n] = __builtin_amdgcn_mfma_f32_16x16x32_bf16(a0h, bh, acc[0][n], 0, 0, 0);
                acc[1][n] = __builtin_amdgcn_mfma_f32_16x16x32_bf16(a1h, bh, acc[1][n], 0, 0, 0);
                acc[0][n] = __builtin_amdgcn_mfma_f32_16x16x32_bf16(a0l, bh, acc[0][n], 0, 0, 0);
                acc[1][n] = __builtin_amdgcn_mfma_f32_16x16x32_bf16(a1l, bh, acc[1][n], 0, 0, 0);
                acc[0][n] = __builtin_amdgcn_mfma_f32_16x16x32_bf16(a0h, bl, acc[0][n], 0, 0, 0);
                acc[1][n] = __builtin_amdgcn_mfma_f32_16x16x32_bf16(a1h, bl, acc[1][n], 0, 0, 0);
            }
        }
    }

    // ---- epilogue: stage C in LDS, then contiguous 512B-row stores ----
    __syncthreads();
    float* Cs = (float*)ABuf;          // [64][128], 32 KB
#pragma unroll
    for (int m = 0; m < 2; ++m) {
        const int rb = wr * 32 + m * 16 + lg * 4;
#pragma unroll
        for (int n = 0; n < 2; ++n) {
            const int col = wc * 32 + n * 16 + lr;
#pragma unroll
            for (int vi = 0; vi < 4; ++vi)
                Cs[(rb + vi) * 128 + col] = acc[m][n][vi];
        }
    }
    __syncthreads();
#pragma unroll
    for (int r4 = 0; r4 < 4; ++r4) {
        const int fi = (r4 * 512 + tid) * 4;     // flat float idx
        const int row = fi >> 7, col = fi & 127;
        if (row0 + row < NN) {
            float4 v = *(float4*)&Cs[fi];
            const float4 b = *(const float4*)&bias[col];
            v.x += b.x; v.y += b.y; v.z += b.z; v.w += b.w;
            *(float4*)&out[(size_t)(row0 + row) * D + col] = v;
        }
    }
}

// ============================================================================
extern "C" void kernel_launch(void* const* d_in, const int* in_sizes, int n_in,
                              void* d_out, int out_size, void* d_ws, size_t ws_size,
                              hipStream_t stream) {
    const float* x      = (const float*)d_in[0];
    const int*   eidx   = (const int*)d_in[1];
    const int*   etyp   = (const int*)d_in[2];
    const float* W      = (const float*)d_in[3];   // [L][R][D][D]
    const float* roots  = (const float*)d_in[4];   // [L][D][D]
    const float* biases = (const float*)d_in[5];   // [L][D]
    float*       out    = (float*)d_out;

    const int* src = eidx;
    const int* dst = eidx + NE;

    // workspace layout (~122 MB)
    float*  bufA = (float*)d_ws;                     // N*D
    float*  bufB = bufA + (size_t)NN * D;            // N*D
    int*    ptr  = (int*)(bufB + (size_t)NN * D);    // NR+1
    int*    fill = ptr + NR + 1;                     // NR
    float*  invp = (float*)(fill + NR);              // NR
    int*    cnt  = (int*)(invp + NR);                // NR
    int*    pos  = cnt + NR;                         // NR
    int*    bsum = pos + NR;                         // 512
    int*    boff = bsum + 512;                       // 512
    int*    ssrc = boff + 512;                       // NE
    ushort* WtH  = (ushort*)(ssrc + NE);             // 18*128*128
    ushort* WtL  = WtH + (size_t)L * 6 * D * D;      // 18*128*128

    hipMemsetAsync(cnt, 0, sizeof(int) * (size_t)NR, stream);
    count_kernel<<<(NE + 255) / 256, 256, 0, stream>>>(dst, etyp, cnt);
    scan1_kernel<<<NB1, 256, 0, stream>>>(cnt, pos, bsum);
    scan2_kernel<<<1, 512, 0, stream>>>(bsum, boff);
    scan3_kernel<<<(NR + 255) / 256, 256, 0, stream>>>(pos, boff, cnt, ptr, fill, invp);
    bucket_kernel<<<(NE + 255) / 256, 256, 0, stream>>>(src, dst, etyp, fill, ssrc);
    wprep_kernel<<<L * 6, 256, 0, stream>>>(W, roots, WtH, WtL);

    const dim3 lgrid((NN + TR - 1) / TR);
    rgcn_layer<0><<<lgrid, 512, 0, stream>>>(x,    WtH + 0 * (size_t)6 * D * D,
                                             WtL + 0 * (size_t)6 * D * D, biases + 0 * D,
                                             ptr, ssrc, invp, bufA);
    rgcn_layer<1><<<lgrid, 512, 0, stream>>>(bufA, WtH + 1 * (size_t)6 * D * D,
                                             WtL + 1 * (size_t)6 * D * D, biases + 1 * D,
                                             ptr, ssrc, invp, bufB);
    rgcn_layer<1><<<lgrid, 512, 0, stream>>>(bufB, WtH + 2 * (size_t)6 * D * D,
                                             WtL + 2 * (size_t)6 * D * D, biases + 2 * D,
                                             ptr, ssrc, invp, out);
}

// Round 9
// 1040.215 us; speedup vs baseline: 3.9394x; 2.5648x over previous
//
#include <hip/hip_runtime.h>

#define NN 100000
#define NE 1600000
#define D  128
#define R  5
#define L  3
#define NR (NN * R)          // 500000 segments
#define NB1 489              // ceil(NR / 1024)
#define PADK 136             // bf16 per LDS A-row (128 + 8 pad)
#define TR 64                // tile rows (nodes per block)

typedef __attribute__((ext_vector_type(8))) short bf16x8;
typedef __attribute__((ext_vector_type(4))) float f32x4;

// ============================================================================
// Prepass: CSR keyed by seg = rel*NN + dst (rel-major: each phase reads one
// contiguous per-node segment). Payload = plain src index.
// ============================================================================
__global__ __launch_bounds__(256) void count_kernel(const int* __restrict__ dst,
                                                    const int* __restrict__ et,
                                                    int* __restrict__ cnt) {
    int e = blockIdx.x * 256 + threadIdx.x;
    if (e < NE) atomicAdd(&cnt[et[e] * NN + dst[e]], 1);
}

__global__ __launch_bounds__(256) void scan1_kernel(const int* __restrict__ cnt,
                                                    int* __restrict__ pos,
                                                    int* __restrict__ bsum) {
    __shared__ int sh[256];
    const int b = blockIdx.x, t = threadIdx.x;
    const int base = b * 1024 + t * 4;
    int v[4], s = 0;
#pragma unroll
    for (int i = 0; i < 4; ++i) {
        v[i] = (base + i < NR) ? cnt[base + i] : 0;
        s += v[i];
    }
    sh[t] = s;
    __syncthreads();
    for (int off = 1; off < 256; off <<= 1) {
        int x = (t >= off) ? sh[t - off] : 0;
        __syncthreads();
        sh[t] += x;
        __syncthreads();
    }
    int run = sh[t] - s;
    if (t == 255) bsum[b] = sh[255];
#pragma unroll
    for (int i = 0; i < 4; ++i) {
        if (base + i < NR) pos[base + i] = run;
        run += v[i];
    }
}

__global__ __launch_bounds__(512) void scan2_kernel(const int* __restrict__ bsum,
                                                    int* __restrict__ boff) {
    __shared__ int sh[512];
    const int t = threadIdx.x;
    int v = (t < NB1) ? bsum[t] : 0;
    sh[t] = v;
    __syncthreads();
    for (int off = 1; off < 512; off <<= 1) {
        int x = (t >= off) ? sh[t - off] : 0;
        __syncthreads();
        sh[t] += x;
        __syncthreads();
    }
    if (t < NB1) boff[t] = sh[t] - v;
}

__global__ __launch_bounds__(256) void scan3_kernel(const int* __restrict__ pos,
                                                    const int* __restrict__ boff,
                                                    const int* __restrict__ cnt,
                                                    int* __restrict__ ptr,
                                                    int* __restrict__ fill,
                                                    float* __restrict__ inv) {
    int i = blockIdx.x * 256 + threadIdx.x;
    if (i < NR) {
        int p = pos[i] + boff[i >> 10];
        ptr[i] = p;
        fill[i] = p;
        int c = cnt[i];
        inv[i] = 1.0f / (float)(c > 0 ? c : 1);
    }
    if (i == 0) ptr[NR] = NE;
}

__global__ __launch_bounds__(256) void bucket_kernel(const int* __restrict__ src,
                                                     const int* __restrict__ dst,
                                                     const int* __restrict__ et,
                                                     int* __restrict__ fill,
                                                     int* __restrict__ ssrc) {
    int e = blockIdx.x * 256 + threadIdx.x;
    if (e < NE) {
        int p = atomicAdd(&fill[et[e] * NN + dst[e]], 1);
        ssrc[p] = src[e];
    }
}

// ============================================================================
// Weight prep: transpose + exact bf16 hi/lo split. Wt[mat][col][k].
// ============================================================================
__device__ __forceinline__ void split2(float f0, float f1, uint& hw, uint& lw) {
    uint b0 = __builtin_bit_cast(uint, f0), b1 = __builtin_bit_cast(uint, f1);
    uint h0 = b0 >> 16, h1 = b1 >> 16;
    float r0 = f0 - __builtin_bit_cast(float, h0 << 16);
    float r1 = f1 - __builtin_bit_cast(float, h1 << 16);
    hw = h0 | (h1 << 16);
    lw = (__builtin_bit_cast(uint, r0) >> 16) | (__builtin_bit_cast(uint, r1) & 0xFFFF0000u);
}

__global__ __launch_bounds__(256) void wprep_kernel(const float* __restrict__ W,
                                                    const float* __restrict__ roots,
                                                    ushort* __restrict__ WtH,
                                                    ushort* __restrict__ WtL) {
    const int mat = blockIdx.x;        // 0..17
    const int l = mat / 6, ph = mat % 6;
    const float* S = (ph == 0) ? roots + (size_t)l * D * D
                               : W + ((size_t)l * R + (ph - 1)) * D * D;
    const int t = threadIdx.x;
    const int dc = t & 127;
    const int half = t >> 7;
    uint* oh = (uint*)(WtH + ((size_t)mat * D + dc) * D) + half * 32;
    uint* ol = (uint*)(WtL + ((size_t)mat * D + dc) * D) + half * 32;
#pragma unroll 4
    for (int j = 0; j < 32; ++j) {
        int dk = half * 64 + j * 2;
        uint hw, lw;
        split2(S[(size_t)dk * D + dc], S[(size_t)(dk + 1) * D + dc], hw, lw);
        oh[j] = hw;
        ol[j] = lw;
    }
}

// ============================================================================
// Cast kernel: hB = bf16_rne(relu(h)).  25.6 MB table, L3-hot; halves the
// gather line count and removes relu from the inner loop.
// ============================================================================
__device__ __forceinline__ uint rne1(float f) {
    uint u = __builtin_bit_cast(uint, f);
    return (u + 0x7FFFu + ((u >> 16) & 1u)) >> 16;
}
__device__ __forceinline__ uint rnepack(float f0, float f1) {
    return rne1(f0) | (rne1(f1) << 16);
}

template <int RELU>
__global__ __launch_bounds__(256) void cast_kernel(const float* __restrict__ h,
                                                   ushort* __restrict__ hB) {
    const int i = blockIdx.x * 256 + threadIdx.x;      // 8 floats per thread
    if (i >= NN * D / 8) return;
    const float4* p = (const float4*)(h + (size_t)i * 8);
    float4 a = p[0], b = p[1];
    if (RELU) {
        a.x = fmaxf(a.x, 0.f); a.y = fmaxf(a.y, 0.f);
        a.z = fmaxf(a.z, 0.f); a.w = fmaxf(a.w, 0.f);
        b.x = fmaxf(b.x, 0.f); b.y = fmaxf(b.y, 0.f);
        b.z = fmaxf(b.z, 0.f); b.w = fmaxf(b.w, 0.f);
    }
    uint4 o;
    o.x = rnepack(a.x, a.y);
    o.y = rnepack(a.z, a.w);
    o.z = rnepack(b.x, b.y);
    o.w = rnepack(b.z, b.w);
    *(uint4*)&hB[(size_t)i * 8] = o;
}

// ============================================================================
// Fused layer (node-parallel gather, R3 structure + bf16 gather + unroll-2):
//   phase 0 (root): fp32 h[node] + relu, exact split -> A-tile, MFMA vs root.
//   phase 1..5 (rel r): 8-lane group walks node's contiguous segment in hB
//     (256B rows, 2 edges per iteration -> 4x16B loads in flight), fp32
//     accumulate, mean, split -> A-tile, MFMA vs W_r.
// LDS 34 KB -> 4 blocks/CU; launch_bounds(512,4) gives VGPR headroom (no
// spill); 8 waves (2x4) each own a 32x32 output sub-tile.
// ============================================================================
#define BFLO(u) __builtin_bit_cast(float, (uint)((u) << 16))
#define BFHI(u) __builtin_bit_cast(float, (uint)((u) & 0xFFFF0000u))
#define ACC8(fa, off, u4)                         \
    do {                                          \
        fa[(off) + 0] += BFLO((u4).x);            \
        fa[(off) + 1] += BFHI((u4).x);            \
        fa[(off) + 2] += BFLO((u4).y);            \
        fa[(off) + 3] += BFHI((u4).y);            \
        fa[(off) + 4] += BFLO((u4).z);            \
        fa[(off) + 5] += BFHI((u4).z);            \
        fa[(off) + 6] += BFLO((u4).w);            \
        fa[(off) + 7] += BFHI((u4).w);            \
    } while (0)

template <int RELU>
__global__ __launch_bounds__(512, 4) void rgcn_layer(
    const float* __restrict__ h, const ushort* __restrict__ hB,
    const ushort* __restrict__ WtH, const ushort* __restrict__ WtL,
    const float* __restrict__ bias, const int* __restrict__ ptr,
    const int* __restrict__ ssrc, const float* __restrict__ inv,
    float* __restrict__ out) {
    __shared__ __align__(16) ushort ABuf[2 * TR * PADK];   // 34816 B
    ushort* Ahi = ABuf;
    ushort* Alo = ABuf + TR * PADK;

    const int tid  = threadIdx.x;
    const int row0 = blockIdx.x * TR;
    const int lane = tid & 63;
    const int wv   = tid >> 6;
    const int wr   = wv & 1;           // 32-row group
    const int wc   = wv >> 1;          // 32-col group
    const int g    = tid >> 3;         // 0..63: node slot
    const int aq   = tid & 7;          // 16-feature slice
    const int lr   = lane & 15;
    const int lg   = lane >> 4;

    f32x4 acc[2][2];
#pragma unroll
    for (int m = 0; m < 2; ++m)
#pragma unroll
        for (int n = 0; n < 2; ++n) acc[m][n] = (f32x4){0.f, 0.f, 0.f, 0.f};

#pragma unroll 1
    for (int ph = 0; ph < 6; ++ph) {
        __syncthreads();   // previous phase done reading the A-tile

        float vv[16];
        const int node = row0 + g;

        if (ph == 0) {
            // ---- root: fp32 row + relu (exact) ----
#pragma unroll
            for (int i = 0; i < 16; ++i) vv[i] = 0.f;
            if (node < NN) {
                const float4* hp = (const float4*)(h + (size_t)node * D + aq * 16);
#pragma unroll
                for (int i = 0; i < 4; ++i) {
                    float4 t4 = hp[i];
                    if (RELU) {
                        t4.x = fmaxf(t4.x, 0.f); t4.y = fmaxf(t4.y, 0.f);
                        t4.z = fmaxf(t4.z, 0.f); t4.w = fmaxf(t4.w, 0.f);
                    }
                    vv[i * 4 + 0] = t4.x; vv[i * 4 + 1] = t4.y;
                    vv[i * 4 + 2] = t4.z; vv[i * 4 + 3] = t4.w;
                }
            }
        } else {
            // ---- neighbor mean from bf16 table, 2-edge unrolled ----
            float fa[16];
#pragma unroll
            for (int i = 0; i < 16; ++i) fa[i] = 0.f;
            float sc = 0.f;
            if (node < NN) {
                const int seg = (ph - 1) * NN + node;
                const int e0 = ptr[seg], e1 = ptr[seg + 1];
                sc = inv[seg];
                const int boff = aq * 16;          // ushort offset in row
                int e = e0;
                for (; e + 2 <= e1; e += 2) {
                    const int s0 = ssrc[e], s1 = ssrc[e + 1];
                    const uint4* r0 = (const uint4*)&hB[(size_t)s0 * D + boff];
                    const uint4* r1 = (const uint4*)&hB[(size_t)s1 * D + boff];
                    const uint4 p0 = r0[0], p1 = r0[1];
                    const uint4 q0 = r1[0], q1 = r1[1];
                    ACC8(fa, 0, p0); ACC8(fa, 8, p1);
                    ACC8(fa, 0, q0); ACC8(fa, 8, q1);
                }
                if (e < e1) {
                    const int s0 = ssrc[e];
                    const uint4* r0 = (const uint4*)&hB[(size_t)s0 * D + boff];
                    const uint4 p0 = r0[0], p1 = r0[1];
                    ACC8(fa, 0, p0); ACC8(fa, 8, p1);
                }
            }
#pragma unroll
            for (int i = 0; i < 16; ++i) vv[i] = fa[i] * sc;
        }

        // ---- exact split to bf16 hi/lo, write A-tile (b128) ----
        {
            uint4 H0, L0, H1, L1;
            split2(vv[0],  vv[1],  H0.x, L0.x);
            split2(vv[2],  vv[3],  H0.y, L0.y);
            split2(vv[4],  vv[5],  H0.z, L0.z);
            split2(vv[6],  vv[7],  H0.w, L0.w);
            split2(vv[8],  vv[9],  H1.x, L1.x);
            split2(vv[10], vv[11], H1.y, L1.y);
            split2(vv[12], vv[13], H1.z, L1.z);
            split2(vv[14], vv[15], H1.w, L1.w);
            const int base = g * PADK + aq * 16;
            *(uint4*)&Ahi[base]     = H0;
            *(uint4*)&Ahi[base + 8] = H1;
            *(uint4*)&Alo[base]     = L0;
            *(uint4*)&Alo[base + 8] = L1;
        }
        __syncthreads();

        // ---- MFMA: acc += A[64x128] * Wt[ph]^T (3-term split) ----
        const ushort* BH = WtH + (size_t)ph * D * D;
        const ushort* BL = WtL + (size_t)ph * D * D;
        const int arow = wr * 32 + lr;
#pragma unroll
        for (int ks = 0; ks < 4; ++ks) {
            const int ak = ks * 32 + lg * 8;
            const bf16x8 a0h = *(const bf16x8*)&Ahi[arow * PADK + ak];
            const bf16x8 a1h = *(const bf16x8*)&Ahi[(arow + 16) * PADK + ak];
            const bf16x8 a0l = *(const bf16x8*)&Alo[arow * PADK + ak];
            const bf16x8 a1l = *(const bf16x8*)&Alo[(arow + 16) * PADK + ak];
#pragma unroll
            for (int n = 0; n < 2; ++n) {
                const int bc = wc * 32 + n * 16 + lr;
                const bf16x8 bh = *(const bf16x8*)&BH[(size_t)bc * D + ak];
                const bf16x8 bl = *(const bf16x8*)&BL[(size_t)bc * D + ak];
                acc[0][n] = __builtin_amdgcn_mfma_f32_16x16x32_bf16(a0h, bh, acc[0][n], 0, 0, 0);
                acc[1][n] = __builtin_amdgcn_mfma_f32_16x16x32_bf16(a1h, bh, acc[1][n], 0, 0, 0);
                acc[0][n] = __builtin_amdgcn_mfma_f32_16x16x32_bf16(a0l, bh, acc[0][n], 0, 0, 0);
                acc[1][n] = __builtin_amdgcn_mfma_f32_16x16x32_bf16(a1l, bh, acc[1][n], 0, 0, 0);
                acc[0][n] = __builtin_amdgcn_mfma_f32_16x16x32_bf16(a0h, bl, acc[0][n], 0, 0, 0);
                acc[1][n] = __builtin_amdgcn_mfma_f32_16x16x32_bf16(a1h, bl, acc[1][n], 0, 0, 0);
            }
        }
    }

    // ---- epilogue: stage C in LDS, then contiguous 512B-row stores ----
    __syncthreads();
    float* Cs = (float*)ABuf;          // [64][128], 32 KB overlay
#pragma unroll
    for (int m = 0; m < 2; ++m) {
        const int rb = wr * 32 + m * 16 + lg * 4;
#pragma unroll
        for (int n = 0; n < 2; ++n) {
            const int col = wc * 32 + n * 16 + lr;
#pragma unroll
            for (int vi = 0; vi < 4; ++vi)
                Cs[(rb + vi) * 128 + col] = acc[m][n][vi];
        }
    }
    __syncthreads();
#pragma unroll
    for (int r4 = 0; r4 < 4; ++r4) {
        const int fi = (r4 * 512 + tid) * 4;     // flat float idx
        const int row = fi >> 7, col = fi & 127;
        if (row0 + row < NN) {
            float4 v = *(float4*)&Cs[fi];
            const float4 b = *(const float4*)&bias[col];
            v.x += b.x; v.y += b.y; v.z += b.z; v.w += b.w;
            *(float4*)&out[(size_t)(row0 + row) * D + col] = v;
        }
    }
}

// ============================================================================
extern "C" void kernel_launch(void* const* d_in, const int* in_sizes, int n_in,
                              void* d_out, int out_size, void* d_ws, size_t ws_size,
                              hipStream_t stream) {
    const float* x      = (const float*)d_in[0];
    const int*   eidx   = (const int*)d_in[1];
    const int*   etyp   = (const int*)d_in[2];
    const float* W      = (const float*)d_in[3];   // [L][R][D][D]
    const float* roots  = (const float*)d_in[4];   // [L][D][D]
    const float* biases = (const float*)d_in[5];   // [L][D]
    float*       out    = (float*)d_out;

    const int* src = eidx;
    const int* dst = eidx + NE;

    // workspace layout (~148 MB)
    float*  bufA = (float*)d_ws;                     // N*D fp32
    float*  bufB = bufA + (size_t)NN * D;            // N*D fp32
    int*    ptr  = (int*)(bufB + (size_t)NN * D);    // NR+1
    int*    fill = ptr + NR + 1;                     // NR
    float*  invp = (float*)(fill + NR);              // NR
    int*    cnt  = (int*)(invp + NR);                // NR
    int*    pos  = cnt + NR;                         // NR
    int*    bsum = pos + NR;                         // 512
    int*    boff = bsum + 512;                       // 512
    int*    ssrc = boff + 512;                       // NE
    ushort* WtH  = (ushort*)(ssrc + NE);             // 18*128*128
    ushort* WtL  = WtH + (size_t)L * 6 * D * D;      // 18*128*128
    ushort* hB   = WtL + (size_t)L * 6 * D * D;      // N*D bf16 (25.6 MB)

    hipMemsetAsync(cnt, 0, sizeof(int) * (size_t)NR, stream);
    count_kernel<<<(NE + 255) / 256, 256, 0, stream>>>(dst, etyp, cnt);
    scan1_kernel<<<NB1, 256, 0, stream>>>(cnt, pos, bsum);
    scan2_kernel<<<1, 512, 0, stream>>>(bsum, boff);
    scan3_kernel<<<(NR + 255) / 256, 256, 0, stream>>>(pos, boff, cnt, ptr, fill, invp);
    bucket_kernel<<<(NE + 255) / 256, 256, 0, stream>>>(src, dst, etyp, fill, ssrc);
    wprep_kernel<<<L * 6, 256, 0, stream>>>(W, roots, WtH, WtL);

    const dim3 cgrid((NN * D / 8 + 255) / 256);
    const dim3 lgrid((NN + TR - 1) / TR);

    // layer 0: input x (no relu)
    cast_kernel<0><<<cgrid, 256, 0, stream>>>(x, hB);
    rgcn_layer<0><<<lgrid, 512, 0, stream>>>(x, hB,
                                             WtH + 0 * (size_t)6 * D * D,
                                             WtL + 0 * (size_t)6 * D * D, biases + 0 * D,
                                             ptr, ssrc, invp, bufA);
    // layer 1: input relu(bufA)
    cast_kernel<1><<<cgrid, 256, 0, stream>>>(bufA, hB);
    rgcn_layer<1><<<lgrid, 512, 0, stream>>>(bufA, hB,
                                             WtH + 1 * (size_t)6 * D * D,
                                             WtL + 1 * (size_t)6 * D * D, biases + 1 * D,
                                             ptr, ssrc, invp, bufB);
    // layer 2: input relu(bufB)
    cast_kernel<1><<<cgrid, 256, 0, stream>>>(bufB, hB);
    rgcn_layer<1><<<lgrid, 512, 0, stream>>>(bufB, hB,
                                             WtH + 2 * (size_t)6 * D * D,
                                             WtL + 2 * (size_t)6 * D * D, biases + 2 * D,
                                             ptr, ssrc, invp, out);
}